// Round 8
// baseline (439.499 us; speedup 1.0000x reference)
//
#include <hip/hip_runtime.h>
#include <hip/hip_bf16.h>

#define Bn   32
#define HWn  676
#define Cn   768
#define Mn   32
#define NC   200
#define KT   (Mn*Cn)      // 24576

#define LOGITS_OFF 0
#define ATTN_OFF   (Bn*NC)                 // 6400
#define EMB_OFF    (ATTN_OFF + Bn*HWn*Mn)  // 698624

// ws layout (float offsets)
#define FT_OFF 0
#define LP_OFF (FT_OFF + Bn*KT)            // 786432
#define NP_OFF (LP_OFF + 64*6400)          // +409600

__device__ __forceinline__ float ssq(float s) {
    return copysignf(sqrtf(fabsf(s) + 1e-12f), s);
}

// load 32 floats (8 float4) from a wave-uniform row pointer
#define LOADROW(dst, ptr) do { _Pragma("unroll") \
    for (int _i = 0; _i < 8; ++_i) \
        dst[_i] = *reinterpret_cast<const float4*>((ptr) + _i * 4); } while (0)

// acc8[0..7] (32 m) += w[0..7] * xv
#define FMAC8(A, W, XV) do { _Pragma("unroll") \
    for (int _i = 0; _i < 8; ++_i) { \
        A[_i].x = fmaf(W[_i].x, (XV), A[_i].x); \
        A[_i].y = fmaf(W[_i].y, (XV), A[_i].y); \
        A[_i].z = fmaf(W[_i].z, (XV), A[_i].z); \
        A[_i].w = fmaf(W[_i].w, (XV), A[_i].w); } } while (0)

// ---- a: attn GEMM. lane = 1 p, acc = 32 m; 8 waves = 8 k-chunks of 96;
// in-block k-reduce. grid = 32b x 11pt = 352 blocks, 512 thr. ----------------
__global__ __launch_bounds__(512, 4) void a_kernel(const float* __restrict__ f7,
                                                   const float* __restrict__ wA,
                                                   float* __restrict__ attn) {
    __shared__ float red[8][64][36];   // 73728 B
    const int t  = threadIdx.x;
    const int wv = t >> 6;
    const int ln = t & 63;
    const int b  = blockIdx.x / 11;
    const int pt = blockIdx.x % 11;
    const int p0 = pt * 64;
    int p = p0 + ln; if (p > HWn - 1) p = HWn - 1;   // clamp (store guarded)
    const int kb = wv * 96;
    const float* xrow = f7 + ((size_t)b * HWn + p) * Cn + kb;
    const float* wb0  = wA + (size_t)kb * Mn;

    float4 acc8[8];
    #pragma unroll
    for (int i = 0; i < 8; ++i) acc8[i] = make_float4(0.f, 0.f, 0.f, 0.f);

    float4 xa, xb, wva[8], wvb[8];
    xa = *reinterpret_cast<const float4*>(xrow);
    LOADROW(wva, wb0);
    #pragma unroll 1
    for (int k4 = 0; k4 < 23; ++k4) {
        const float* wkb = wb0 + (size_t)(k4 * 4) * Mn;
        xb = *reinterpret_cast<const float4*>(xrow + (k4 + 1) * 4);
        LOADROW(wvb, wkb + Mn);
        FMAC8(acc8, wva, xa.x);
        LOADROW(wva, wkb + 2 * Mn);
        FMAC8(acc8, wvb, xa.y);
        LOADROW(wvb, wkb + 3 * Mn);
        FMAC8(acc8, wva, xa.z);
        LOADROW(wva, wkb + 4 * Mn);   // next k4's row 0
        FMAC8(acc8, wvb, xa.w);
        xa = xb;
    }
    {   // k4 = 23 tail
        const float* wkb = wb0 + (size_t)(23 * 4) * Mn;
        LOADROW(wvb, wkb + Mn);
        FMAC8(acc8, wva, xa.x);
        LOADROW(wva, wkb + 2 * Mn);
        FMAC8(acc8, wvb, xa.y);
        LOADROW(wvb, wkb + 3 * Mn);
        FMAC8(acc8, wva, xa.z);
        FMAC8(acc8, wvb, xa.w);
    }

    #pragma unroll
    for (int i = 0; i < 8; ++i)
        *reinterpret_cast<float4*>(&red[wv][ln][i * 4]) = acc8[i];
    __syncthreads();

    // reduce 8 k-chunks; thread = (p-row, m-quad)
    const int pp = t >> 3;
    const int m0 = (t & 7) * 4;
    float4 s = make_float4(0.f, 0.f, 0.f, 0.f);
    #pragma unroll
    for (int w = 0; w < 8; ++w) {
        float4 v = *reinterpret_cast<const float4*>(&red[w][pp][m0]);
        s.x += v.x; s.y += v.y; s.z += v.z; s.w += v.w;
    }
    const int gp = p0 + pp;
    if (gp < HWn)
        *reinterpret_cast<float4*>(attn + ((size_t)b * HWn + gp) * Mn + m0) = s;
}

// ---- b: pooling GEMM. lane = 1 c, acc = 32 m; 8 waves = 8 p-chunks of 85;
// in-block p-reduce + fused ssqrt/featT/norm. grid = 32b x 12ct = 384, 512 thr.
__global__ __launch_bounds__(512, 4) void b_kernel(const float* __restrict__ f6,
                                                   const float* __restrict__ attn,
                                                   float* __restrict__ emb,
                                                   float* __restrict__ featT,
                                                   float* __restrict__ norm_part) {
    __shared__ float red[8][64][36];   // 73728 B
    const int t  = threadIdx.x;
    const int wv = t >> 6;
    const int ln = t & 63;
    const int b  = blockIdx.x / 12;
    const int ct = blockIdx.x % 12;
    const int c0 = ct * 64;
    const int ps = wv * 85;
    const int pe = (ps + 85 < HWn) ? (ps + 85) : HWn;
    const float* fcol = f6 + (size_t)b * HWn * Cn + c0 + ln;
    const float* ab   = attn + (size_t)b * HWn * Mn;

    float4 acc8[8];
    #pragma unroll
    for (int i = 0; i < 8; ++i) acc8[i] = make_float4(0.f, 0.f, 0.f, 0.f);

    float4 wva[8], wvb[8];
    LOADROW(wva, ab + (size_t)ps * Mn);
    int p = ps;
    #pragma unroll 1
    for (; p + 1 < pe; p += 2) {
        float xv0 = fcol[(size_t)p * Cn];
        LOADROW(wvb, ab + (size_t)(p + 1) * Mn);
        FMAC8(acc8, wva, xv0);
        float xv1 = fcol[(size_t)(p + 1) * Cn];
        int pn = (p + 2 < pe) ? (p + 2) : (HWn - 1);
        LOADROW(wva, ab + (size_t)pn * Mn);
        FMAC8(acc8, wvb, xv1);
    }
    if (p < pe) {
        float xv = fcol[(size_t)p * Cn];
        FMAC8(acc8, wva, xv);
    }

    #pragma unroll
    for (int i = 0; i < 8; ++i)
        *reinterpret_cast<float4*>(&red[wv][ln][i * 4]) = acc8[i];
    __syncthreads();

    // reduce 8 p-chunks; thread = (c, m-quad); then ssqrt + outputs
    const int cc = t & 63;
    const int m0 = (t >> 6) * 4;
    float4 s = make_float4(0.f, 0.f, 0.f, 0.f);
    #pragma unroll
    for (int w = 0; w < 8; ++w) {
        float4 v = *reinterpret_cast<const float4*>(&red[w][cc][m0]);
        s.x += v.x; s.y += v.y; s.z += v.z; s.w += v.w;
    }
    const float inv = 1.0f / (float)HWn;
    float o0 = ssq(s.x * inv), o1 = ssq(s.y * inv);
    float o2 = ssq(s.z * inv), o3 = ssq(s.w * inv);
    const int gc = c0 + cc;
    {
        size_t k0 = (size_t)(m0 + 0) * Cn + gc;
        size_t k1 = (size_t)(m0 + 1) * Cn + gc;
        size_t k2 = (size_t)(m0 + 2) * Cn + gc;
        size_t k3 = (size_t)(m0 + 3) * Cn + gc;
        float* eb = emb + (size_t)b * KT;
        eb[k0] = o0; eb[k1] = o1; eb[k2] = o2; eb[k3] = o3;
        featT[k0 * Bn + b] = o0;
        featT[k1 * Bn + b] = o1;
        featT[k2 * Bn + b] = o2;
        featT[k3 * Bn + b] = o3;
    }
    float lsq = o0 * o0 + o1 * o1 + o2 * o2 + o3 * o3;
    #pragma unroll
    for (int off = 32; off > 0; off >>= 1) lsq += __shfl_down(lsq, off, 64);
    __syncthreads();
    if ((t & 63) == 0) red[0][0][t >> 6] = lsq;
    __syncthreads();
    if (t == 0) {
        float ns = 0.f;
        #pragma unroll
        for (int w = 0; w < 8; ++w) ns += red[0][0][w];
        norm_part[b * 12 + ct] = ns;
    }
}

// ---- l: partial logits, thread = (b, 4n), k-slice 384. grid 7 x 64. ---------
__global__ __launch_bounds__(256) void l_kernel(const float* __restrict__ featT,
                                                const float* __restrict__ wC,
                                                float* __restrict__ lp) {
    const int t  = threadIdx.x;
    const int ks = blockIdx.x & 63;
    const int nt = blockIdx.x >> 6;   // 0..6
    const int b  = t & 31;
    const int nn = t >> 5;            // 0..7
    const int n  = nt * 32 + nn * 4;
    const int k0 = ks * 384;
    if (n < NC) {
        const float* fp = featT + (size_t)k0 * Bn + b;
        const float* wp = wC + (size_t)k0 * NC + n;
        float4 acc = make_float4(0.f, 0.f, 0.f, 0.f);
        #pragma unroll 8
        for (int k = 0; k < 384; ++k) {
            float  f = fp[(size_t)k * Bn];
            float4 w = *reinterpret_cast<const float4*>(wp + (size_t)k * NC);
            acc.x += f * w.x; acc.y += f * w.y; acc.z += f * w.z; acc.w += f * w.w;
        }
        float* d = lp + (size_t)ks * 6400 + (size_t)n * Bn + b;
        d[0]      = acc.x;
        d[Bn]     = acc.y;
        d[2 * Bn] = acc.z;
        d[3 * Bn] = acc.w;
    }
}

// ---- ln: normalize emb in place. grid 768, 256 thr. -------------------------
__global__ __launch_bounds__(256) void ln_kernel(float* __restrict__ emb,
                                                 const float* __restrict__ norm_part) {
    const int b = blockIdx.x / 24;
    const int o = (blockIdx.x % 24) * 1024 + threadIdx.x * 4;
    float ns = 0.f;
    #pragma unroll
    for (int g = 0; g < 12; ++g) ns += norm_part[b * 12 + g];
    float sc = rsqrtf(fmaxf(ns, 1e-12f));
    float4 v = *reinterpret_cast<float4*>(emb + (size_t)b * KT + o);
    v.x *= sc; v.y *= sc; v.z *= sc; v.w *= sc;
    *reinterpret_cast<float4*>(emb + (size_t)b * KT + o) = v;
}

// ---- lr: logits = sum_ks lp * rsqrt(norm) * 100. grid 25 x 256. -------------
__global__ __launch_bounds__(256) void lr_kernel(const float* __restrict__ lp,
                                                 const float* __restrict__ norm_part,
                                                 float* __restrict__ logits) {
    const int j = blockIdx.x * 256 + threadIdx.x;   // < 6400
    const int b = j & 31;
    const int n = j >> 5;
    float s = 0.f;
    for (int ks = 0; ks < 64; ++ks) s += lp[(size_t)ks * 6400 + j];
    float ns = 0.f;
    #pragma unroll
    for (int g = 0; g < 12; ++g) ns += norm_part[b * 12 + g];
    float sc = rsqrtf(fmaxf(ns, 1e-12f)) * 100.f;
    logits[(size_t)b * NC + n] = s * sc;
}

extern "C" void kernel_launch(void* const* d_in, const int* in_sizes, int n_in,
                              void* d_out, int out_size, void* d_ws, size_t ws_size,
                              hipStream_t stream) {
    const float* f6 = (const float*)d_in[0];
    const float* f7 = (const float*)d_in[1];
    const float* wA = (const float*)d_in[2];
    const float* wC = (const float*)d_in[3];
    float* out = (float*)d_out;
    float* logits = out + LOGITS_OFF;
    float* attn = out + ATTN_OFF;
    float* emb = out + EMB_OFF;

    float* ws = (float*)d_ws;
    float* featT = ws + FT_OFF;
    float* lp = ws + LP_OFF;
    float* norm_part = ws + NP_OFF;

    a_kernel<<<Bn * 11, 512, 0, stream>>>(f7, wA, attn);
    b_kernel<<<Bn * 12, 512, 0, stream>>>(f6, attn, emb, featT, norm_part);
    l_kernel<<<7 * 64, 256, 0, stream>>>(featT, wC, lp);
    ln_kernel<<<768, 256, 0, stream>>>(emb, norm_part);
    lr_kernel<<<25, 256, 0, stream>>>(lp, norm_part, logits);
}

// Round 9
// 112.072 us; speedup vs baseline: 3.9216x; 3.9216x over previous
//
#include <hip/hip_runtime.h>
#include <hip/hip_bf16.h>

#define Bn   32
#define HWn  676
#define Cn   768
#define Mn   32
#define NC   200
#define KT   (Mn*Cn)      // 24576
#define KP   704          // padded position count (22 * 32)

#define LOGITS_OFF 0
#define ATTN_OFF   (Bn*NC)                 // 6400
#define EMB_OFF    (ATTN_OFF + Bn*HWn*Mn)  // 698624

// ws layout (float offsets)
#define WBP_OFF 0                            // 49152 ushort = 24576 f
#define ATH_OFF (WBP_OFF + 24576)            // attnT_hi: 32*32*704 ushort = 360448 f
#define ATL_OFF (ATH_OFF + 360448)
#define FT_OFF  (ATL_OFF + 360448)           // featT f32: 786432
#define LP_OFF  (FT_OFF + 786432)            // 64*6400
#define NP_OFF  (LP_OFF + 64*6400)           // 384

typedef __attribute__((ext_vector_type(8))) short bf16x8;
typedef __attribute__((ext_vector_type(4))) float f32x4;

__device__ __forceinline__ float ssq(float s) {
    return copysignf(sqrtf(fabsf(s) + 1e-12f), s);
}
__device__ __forceinline__ void split2(float x, ushort& h, ushort& l) {
    unsigned xb = __float_as_uint(x);
    h = (ushort)(xb >> 16);
    float r = x - __uint_as_float(xb & 0xFFFF0000u);
    l = (ushort)(__float_as_uint(r) >> 16);
}

// ---- w: pack wA into MFMA B-fragment order, bf16 hi/lo. 1 block. ------------
// frag id = ((nt*24 + ks)*2 + hl)*64 + lane ; elem j: wA[ks*32+(lane>>4)*8+j][nt*16+(lane&15)]
__global__ __launch_bounds__(256) void w_kernel(const float* __restrict__ wA,
                                                ushort* __restrict__ wBp) {
    const int t = threadIdx.x;
    for (int i = 0; i < 24; ++i) {
        int fid = t + 256 * i;          // 0..6143
        int lane = fid & 63;
        int rest = fid >> 6;            // 0..95
        int hl = rest & 1;
        int q  = rest >> 1;             // 0..47
        int ks = q % 24, nt = q / 24;
        int m  = nt * 16 + (lane & 15);
        int kb = ks * 32 + ((lane >> 4) << 3);
        bf16x8 v;
        #pragma unroll
        for (int j = 0; j < 8; ++j) {
            ushort h, l;
            split2(wA[(size_t)(kb + j) * Mn + m], h, l);
            v[j] = (short)(hl ? l : h);
        }
        *reinterpret_cast<bf16x8*>(wBp + (size_t)fid * 8) = v;
    }
}

// ---- a: attn GEMM via MFMA 16x16x32 bf16x3. grid 32b x 11pt, 256 thr. -------
__global__ __launch_bounds__(256, 4) void a_kernel(const float* __restrict__ f7,
                                                   const ushort* __restrict__ wBp,
                                                   float* __restrict__ attn) {
    __shared__ ushort ah[64][40], al[64][40];
    const int t  = threadIdx.x;
    const int wv = t >> 6;
    const int ln = t & 63;
    const int b  = blockIdx.x / 11;
    const int pt = blockIdx.x % 11;
    const int p0 = pt * 64;
    const float* f7b = f7 + (size_t)b * HWn * Cn;

    // staging: f4 idx t and t+256 over [64 rows][8 f4]
    const int r0 = t >> 3, c40 = (t & 7) * 4;
    const int r1 = r0 + 32;
    int gr0 = p0 + r0; if (gr0 > HWn - 1) gr0 = HWn - 1;
    int gr1 = p0 + r1; if (gr1 > HWn - 1) gr1 = HWn - 1;

    const int lrow = (wv << 4) + (ln & 15);   // A row (local p)
    const int kof  = (ln >> 4) << 3;          // k offset 0/8/16/24

    f32x4 acc0 = {0.f, 0.f, 0.f, 0.f};
    f32x4 acc1 = {0.f, 0.f, 0.f, 0.f};
    const bf16x8* BP = reinterpret_cast<const bf16x8*>(wBp);

    float4 x0 = *reinterpret_cast<const float4*>(f7b + (size_t)gr0 * Cn + c40);
    float4 x1 = *reinterpret_cast<const float4*>(f7b + (size_t)gr1 * Cn + c40);

    for (int ks = 0; ks < 24; ++ks) {
        {   // convert + LDS write (8B each)
            ushort h[4], l[4];
            split2(x0.x, h[0], l[0]); split2(x0.y, h[1], l[1]);
            split2(x0.z, h[2], l[2]); split2(x0.w, h[3], l[3]);
            uint2 hw, lw;
            hw.x = h[0] | (h[1] << 16); hw.y = h[2] | (h[3] << 16);
            lw.x = l[0] | (l[1] << 16); lw.y = l[2] | (l[3] << 16);
            *reinterpret_cast<uint2*>(&ah[r0][c40]) = hw;
            *reinterpret_cast<uint2*>(&al[r0][c40]) = lw;
            split2(x1.x, h[0], l[0]); split2(x1.y, h[1], l[1]);
            split2(x1.z, h[2], l[2]); split2(x1.w, h[3], l[3]);
            hw.x = h[0] | (h[1] << 16); hw.y = h[2] | (h[3] << 16);
            lw.x = l[0] | (l[1] << 16); lw.y = l[2] | (l[3] << 16);
            *reinterpret_cast<uint2*>(&ah[r1][c40]) = hw;
            *reinterpret_cast<uint2*>(&al[r1][c40]) = lw;
        }
        __syncthreads();
        if (ks + 1 < 24) {   // prefetch next k-chunk
            int kc = (ks + 1) * 32 + c40;
            x0 = *reinterpret_cast<const float4*>(f7b + (size_t)gr0 * Cn + kc);
            x1 = *reinterpret_cast<const float4*>(f7b + (size_t)gr1 * Cn + kc);
        }
        bf16x8 Ah = *reinterpret_cast<const bf16x8*>(&ah[lrow][kof]);
        bf16x8 Al = *reinterpret_cast<const bf16x8*>(&al[lrow][kof]);
        bf16x8 B0h = BP[(size_t)((0 * 24 + ks) * 2 + 0) * 64 + ln];
        bf16x8 B0l = BP[(size_t)((0 * 24 + ks) * 2 + 1) * 64 + ln];
        bf16x8 B1h = BP[(size_t)((1 * 24 + ks) * 2 + 0) * 64 + ln];
        bf16x8 B1l = BP[(size_t)((1 * 24 + ks) * 2 + 1) * 64 + ln];
        acc0 = __builtin_amdgcn_mfma_f32_16x16x32_bf16(Ah, B0h, acc0, 0, 0, 0);
        acc1 = __builtin_amdgcn_mfma_f32_16x16x32_bf16(Ah, B1h, acc1, 0, 0, 0);
        acc0 = __builtin_amdgcn_mfma_f32_16x16x32_bf16(Ah, B0l, acc0, 0, 0, 0);
        acc1 = __builtin_amdgcn_mfma_f32_16x16x32_bf16(Ah, B1l, acc1, 0, 0, 0);
        acc0 = __builtin_amdgcn_mfma_f32_16x16x32_bf16(Al, B0h, acc0, 0, 0, 0);
        acc1 = __builtin_amdgcn_mfma_f32_16x16x32_bf16(Al, B1h, acc1, 0, 0, 0);
        __syncthreads();
    }
    // C: col(m) = ln&15 (+16*nt), row(p) = p0 + wv*16 + (ln>>4)*4 + r
    #pragma unroll
    for (int r = 0; r < 4; ++r) {
        int p = p0 + (wv << 4) + ((ln >> 4) << 2) + r;
        if (p < HWn) {
            float* dst = attn + ((size_t)b * HWn + p) * Mn + (ln & 15);
            dst[0]  = acc0[r];
            dst[16] = acc1[r];
        }
    }
}

// ---- t2: attn -> attnT hi/lo bf16, [b][m][704], zero-padded. grid 352. ------
__global__ __launch_bounds__(256) void t2_kernel(const float* __restrict__ attn,
                                                 ushort* __restrict__ ath,
                                                 ushort* __restrict__ atl) {
    __shared__ float at[64][33];
    const int t  = threadIdx.x;
    const int b  = blockIdx.x / 11;
    const int pt = blockIdx.x % 11;
    const int p0 = pt * 64;
    #pragma unroll
    for (int i = 0; i < 2; ++i) {
        int idx = t + i * 256;
        int row = idx >> 3, m4 = (idx & 7) * 4;
        int gp = p0 + row;
        float4 v = make_float4(0.f, 0.f, 0.f, 0.f);
        if (gp < HWn)
            v = *reinterpret_cast<const float4*>(attn + ((size_t)b * HWn + gp) * Mn + m4);
        *reinterpret_cast<float4*>(&at[row][m4]) = v;
    }
    __syncthreads();
    const int m  = t >> 3;
    const int pq = (t & 7) * 8;
    bf16x8 hv, lv;
    #pragma unroll
    for (int j = 0; j < 8; ++j) {
        ushort h, l;
        split2(at[pq + j][m], h, l);
        hv[j] = (short)h; lv[j] = (short)l;
    }
    size_t off = ((size_t)b * Mn + m) * KP + p0 + pq;
    *reinterpret_cast<bf16x8*>(ath + off) = hv;
    *reinterpret_cast<bf16x8*>(atl + off) = lv;
}

// ---- b: pooling GEMM via MFMA + fused ssqrt/norm. grid 32b x 12ct, 256 thr. -
__global__ __launch_bounds__(256, 4) void b_kernel(const float* __restrict__ f6,
                                                   const ushort* __restrict__ ath,
                                                   const ushort* __restrict__ atl,
                                                   float* __restrict__ emb,
                                                   float* __restrict__ norm_part) {
    __shared__ ushort fh[64][40], fl[64][40];   // f6T [c][p] bf16
    __shared__ float red[4];
    const int t  = threadIdx.x;
    const int wv = t >> 6;
    const int ln = t & 63;
    const int b  = blockIdx.x / 12;
    const int ct = blockIdx.x % 12;
    const int c0 = ct * 64;
    const float* f6b = f6 + (size_t)b * HWn * Cn + c0;

    // staging: thread covers c-quad cb..cb+3 at rows p=2pp, 2pp+1
    const int cb = (t & 15) * 4;
    const int pp = t >> 4;            // 0..15
    const int cloc = (wv << 4) + (ln & 15);   // B col (local c)
    const int kof  = (ln >> 4) << 3;

    const ushort* a0h = ath + ((size_t)b * Mn + 0  + (ln & 15)) * KP;
    const ushort* a0l = atl + ((size_t)b * Mn + 0  + (ln & 15)) * KP;
    const ushort* a1h = ath + ((size_t)b * Mn + 16 + (ln & 15)) * KP;
    const ushort* a1l = atl + ((size_t)b * Mn + 16 + (ln & 15)) * KP;

    f32x4 acc0 = {0.f, 0.f, 0.f, 0.f};
    f32x4 acc1 = {0.f, 0.f, 0.f, 0.f};

    float4 y0, y1;
    const float4 z4 = make_float4(0.f, 0.f, 0.f, 0.f);
    {
        int g0 = 2 * pp, g1 = 2 * pp + 1;
        y0 = (g0 < HWn) ? *reinterpret_cast<const float4*>(f6b + (size_t)g0 * Cn + cb) : z4;
        y1 = (g1 < HWn) ? *reinterpret_cast<const float4*>(f6b + (size_t)g1 * Cn + cb) : z4;
    }

    for (int s = 0; s < 22; ++s) {
        const int pc = s * 32;
        {   // convert + transposed LDS write: fh[c][p] pairs (p even|odd)
            const float* a_ = reinterpret_cast<const float*>(&y0);
            const float* b_ = reinterpret_cast<const float*>(&y1);
            #pragma unroll
            for (int i = 0; i < 4; ++i) {
                ushort h0, l0, h1, l1;
                split2(a_[i], h0, l0);
                split2(b_[i], h1, l1);
                *reinterpret_cast<unsigned*>(&fh[cb + i][2 * pp]) = h0 | (h1 << 16);
                *reinterpret_cast<unsigned*>(&fl[cb + i][2 * pp]) = l0 | (l1 << 16);
            }
        }
        __syncthreads();
        if (s + 1 < 22) {
            int g0 = (s + 1) * 32 + 2 * pp, g1 = g0 + 1;
            y0 = (g0 < HWn) ? *reinterpret_cast<const float4*>(f6b + (size_t)g0 * Cn + cb) : z4;
            y1 = (g1 < HWn) ? *reinterpret_cast<const float4*>(f6b + (size_t)g1 * Cn + cb) : z4;
        }
        bf16x8 A0h = *reinterpret_cast<const bf16x8*>(a0h + pc + kof);
        bf16x8 A0l = *reinterpret_cast<const bf16x8*>(a0l + pc + kof);
        bf16x8 A1h = *reinterpret_cast<const bf16x8*>(a1h + pc + kof);
        bf16x8 A1l = *reinterpret_cast<const bf16x8*>(a1l + pc + kof);
        bf16x8 Bh  = *reinterpret_cast<const bf16x8*>(&fh[cloc][kof]);
        bf16x8 Bl  = *reinterpret_cast<const bf16x8*>(&fl[cloc][kof]);
        acc0 = __builtin_amdgcn_mfma_f32_16x16x32_bf16(A0h, Bh, acc0, 0, 0, 0);
        acc1 = __builtin_amdgcn_mfma_f32_16x16x32_bf16(A1h, Bh, acc1, 0, 0, 0);
        acc0 = __builtin_amdgcn_mfma_f32_16x16x32_bf16(A0h, Bl, acc0, 0, 0, 0);
        acc1 = __builtin_amdgcn_mfma_f32_16x16x32_bf16(A1h, Bl, acc1, 0, 0, 0);
        acc0 = __builtin_amdgcn_mfma_f32_16x16x32_bf16(A0l, Bh, acc0, 0, 0, 0);
        acc1 = __builtin_amdgcn_mfma_f32_16x16x32_bf16(A1l, Bh, acc1, 0, 0, 0);
        __syncthreads();
    }

    // epilogue: C col(c) = ln&15, row(m) = (ln>>4)*4 + r (+16 for acc1)
    const float inv = 1.0f / (float)HWn;
    const int cg = c0 + cloc;
    float lsq = 0.f;
    #pragma unroll
    for (int r = 0; r < 4; ++r) {
        int m = ((ln >> 4) << 2) + r;
        float o0 = ssq(acc0[r] * inv);
        float o1 = ssq(acc1[r] * inv);
        emb[(size_t)b * KT + (size_t)m * Cn + cg]        = o0;
        emb[(size_t)b * KT + (size_t)(m + 16) * Cn + cg] = o1;
        lsq += o0 * o0 + o1 * o1;
    }
    #pragma unroll
    for (int off = 32; off > 0; off >>= 1) lsq += __shfl_down(lsq, off, 64);
    if ((t & 63) == 0) red[t >> 6] = lsq;
    __syncthreads();
    if (t == 0)
        norm_part[b * 12 + ct] = red[0] + red[1] + red[2] + red[3];
}

// ---- t: featT[k][b] from emb, LDS-tiled coalesced transpose. grid 384. ------
__global__ __launch_bounds__(256) void t_kernel(const float* __restrict__ emb,
                                                float* __restrict__ featT) {
    __shared__ float et[32][68];
    const int t = threadIdx.x;
    const int k0 = blockIdx.x * 64;
    #pragma unroll
    for (int i = 0; i < 2; ++i) {
        int idx = t + i * 256;
        int bb = idx >> 4, k4 = (idx & 15) * 4;
        float4 v = *reinterpret_cast<const float4*>(emb + (size_t)bb * KT + k0 + k4);
        *reinterpret_cast<float4*>(&et[bb][k4]) = v;
    }
    __syncthreads();
    #pragma unroll
    for (int i = 0; i < 2; ++i) {
        int idx = t + i * 256;
        int k = idx >> 3, b4 = (idx & 7) * 4;
        float4 o = make_float4(et[b4][k], et[b4 + 1][k], et[b4 + 2][k], et[b4 + 3][k]);
        *reinterpret_cast<float4*>(featT + (size_t)(k0 + k) * Bn + b4) = o;
    }
}

// ---- l: partial logits, thread = (b, 4n), k-slice 384. grid 7 x 64. ---------
__global__ __launch_bounds__(256) void l_kernel(const float* __restrict__ featT,
                                                const float* __restrict__ wC,
                                                float* __restrict__ lp) {
    const int t  = threadIdx.x;
    const int ks = blockIdx.x & 63;
    const int nt = blockIdx.x >> 6;
    const int b  = t & 31;
    const int nn = t >> 5;
    const int n  = nt * 32 + nn * 4;
    const int k0 = ks * 384;
    if (n < NC) {
        const float* fp = featT + (size_t)k0 * Bn + b;
        const float* wp = wC + (size_t)k0 * NC + n;
        float4 acc = make_float4(0.f, 0.f, 0.f, 0.f);
        #pragma unroll 8
        for (int k = 0; k < 384; ++k) {
            float  f = fp[(size_t)k * Bn];
            float4 w = *reinterpret_cast<const float4*>(wp + (size_t)k * NC);
            acc.x += f * w.x; acc.y += f * w.y; acc.z += f * w.z; acc.w += f * w.w;
        }
        float* d = lp + (size_t)ks * 6400 + (size_t)n * Bn + b;
        d[0]      = acc.x;
        d[Bn]     = acc.y;
        d[2 * Bn] = acc.z;
        d[3 * Bn] = acc.w;
    }
}

// ---- ln: normalize emb in place. grid 768. ----------------------------------
__global__ __launch_bounds__(256) void ln_kernel(float* __restrict__ emb,
                                                 const float* __restrict__ norm_part) {
    const int b = blockIdx.x / 24;
    const int o = (blockIdx.x % 24) * 1024 + threadIdx.x * 4;
    float ns = 0.f;
    #pragma unroll
    for (int g = 0; g < 12; ++g) ns += norm_part[b * 12 + g];
    float sc = rsqrtf(fmaxf(ns, 1e-12f));
    float4 v = *reinterpret_cast<float4*>(emb + (size_t)b * KT + o);
    v.x *= sc; v.y *= sc; v.z *= sc; v.w *= sc;
    *reinterpret_cast<float4*>(emb + (size_t)b * KT + o) = v;
}

// ---- lr: logits = sum_ks lp * rsqrt(norm) * 100. grid 25. -------------------
__global__ __launch_bounds__(256) void lr_kernel(const float* __restrict__ lp,
                                                 const float* __restrict__ norm_part,
                                                 float* __restrict__ logits) {
    const int j = blockIdx.x * 256 + threadIdx.x;
    const int b = j & 31;
    const int n = j >> 5;
    float s = 0.f;
    for (int ks = 0; ks < 64; ++ks) s += lp[(size_t)ks * 6400 + j];
    float ns = 0.f;
    #pragma unroll
    for (int g = 0; g < 12; ++g) ns += norm_part[b * 12 + g];
    float sc = rsqrtf(fmaxf(ns, 1e-12f)) * 100.f;
    logits[(size_t)b * NC + n] = s * sc;
}

extern "C" void kernel_launch(void* const* d_in, const int* in_sizes, int n_in,
                              void* d_out, int out_size, void* d_ws, size_t ws_size,
                              hipStream_t stream) {
    const float* f6 = (const float*)d_in[0];
    const float* f7 = (const float*)d_in[1];
    const float* wA = (const float*)d_in[2];
    const float* wC = (const float*)d_in[3];
    float* out = (float*)d_out;
    float* logits = out + LOGITS_OFF;
    float* attn = out + ATTN_OFF;
    float* emb = out + EMB_OFF;

    float* ws = (float*)d_ws;
    ushort* wBp = (ushort*)(ws + WBP_OFF);
    ushort* ath = (ushort*)(ws + ATH_OFF);
    ushort* atl = (ushort*)(ws + ATL_OFF);
    float* featT = ws + FT_OFF;
    float* lp = ws + LP_OFF;
    float* norm_part = ws + NP_OFF;

    w_kernel<<<1, 256, 0, stream>>>(wA, wBp);
    a_kernel<<<Bn * 11, 256, 0, stream>>>(f7, wBp, attn);
    t2_kernel<<<Bn * 11, 256, 0, stream>>>(attn, ath, atl);
    b_kernel<<<Bn * 12, 256, 0, stream>>>(f6, ath, atl, emb, norm_part);
    t_kernel<<<384, 256, 0, stream>>>(emb, featT);
    l_kernel<<<7 * 64, 256, 0, stream>>>(featT, wC, lp);
    ln_kernel<<<768, 256, 0, stream>>>(emb, norm_part);
    lr_kernel<<<25, 256, 0, stream>>>(lp, norm_part, logits);
}